// Round 22
// baseline (65.394 us; speedup 1.0000x reference)
//
#include <hip/hip_runtime.h>

#define NB 16     // batch
#define CD 128    // channels
#define HW 4096   // spatial L
#define DD 512    // projected dim
#define KC 64     // clusters

typedef __attribute__((ext_vector_type(8))) short bfrag;           // 8 bf16 (4 VGPR)
typedef __attribute__((ext_vector_type(4))) float facc;            // MFMA acc

__device__ __forceinline__ unsigned short f2bf(float f) {
  union { float f; unsigned u; } v; v.f = f;
  unsigned r = v.u + 0x7fffu + ((v.u >> 16) & 1u);   // RNE
  return (unsigned short)(r >> 16);
}
__device__ __forceinline__ float bf2f(unsigned short h) {
  union { unsigned u; float f; } v; v.u = ((unsigned)h) << 16; return v.f;
}
// packed f32x2 -> bf16x2 (RNE), low16 = lo
__device__ __forceinline__ unsigned f2bf2(float lo, float hi) {
  unsigned r;
  asm("v_cvt_pk_bf16_f32 %0, %1, %2" : "=v"(r) : "v"(lo), "v"(hi));
  return r;
}
// async global->LDS: HW writes lds_base + lane*16; global src carries per-lane offset
__device__ __forceinline__ void gll16(const void* g, void* l) {
  __builtin_amdgcn_global_load_lds(
      (__attribute__((address_space(1))) void*)(uintptr_t)g,
      (__attribute__((address_space(3))) void*)(uintptr_t)l, 16, 0, 0);
}
// row swizzle: spreads row-parallel accesses across 8 16B slots
__device__ __forceinline__ int swzr(int r) { return ((r & 7) ^ ((r >> 3) & 7)) << 4; }

// ---------- prep (merged): M/bk rows (blocks 0..63) + Wsw images (blocks 64..95) ----------
// M[k][c] = inv_k * sum_d centroids[k][d]*W[d][c] (bf16); bk[k] = inv_k * (centroids[k].b)
// Wsw: 8 images x [64d x 256B], byte = dch*16384 + dl*256 + ((c*2)^swzr(dl))
__global__ __launch_bounds__(256) void k_prep(const float* __restrict__ conv_w,
                                              const float* __restrict__ conv_b,
                                              const float* __restrict__ centroids,
                                              unsigned short* __restrict__ Wsw,
                                              unsigned short* __restrict__ Mg,
                                              float* __restrict__ bk) {
  int b = blockIdx.x, t = threadIdx.x;
  if (b < KC) {
    __shared__ float red[4];
    __shared__ float sinv;
    __shared__ float mred[256];
    const float* row = centroids + (size_t)b * DD;
    float v0 = row[t], v1 = row[t + 256];
    float ss = v0 * v0 + v1 * v1;
    #pragma unroll
    for (int off = 32; off; off >>= 1) ss += __shfl_xor(ss, off);
    if ((t & 63) == 0) red[t >> 6] = ss;
    __syncthreads();
    if (t == 0) sinv = 1.0f / fmaxf(sqrtf(red[0] + red[1] + red[2] + red[3]), 1e-12f);
    __syncthreads();
    float inv = sinv;
    int dd = t >> 7, c = t & 127;
    float macc = 0.f;
    #pragma unroll 16
    for (int d0 = 0; d0 < DD; d0 += 2) {
      float cn = row[d0 + dd];
      macc += cn * conv_w[(size_t)(d0 + dd) * CD + c];
    }
    mred[t] = macc;
    float bp = v0 * conv_b[t] + v1 * conv_b[t + 256];
    #pragma unroll
    for (int off = 32; off; off >>= 1) bp += __shfl_xor(bp, off);
    if ((t & 63) == 0) red[t >> 6] = bp;
    __syncthreads();
    if (t < 128) Mg[(size_t)b * CD + t] = f2bf((mred[t] + mred[t + 128]) * inv);
    if (t == 0) bk[b] = (red[0] + red[1] + red[2] + red[3]) * inv;
  } else {
    int i = (b - KC) * 2048 + t * 8;            // 32 blocks cover 512x128
    const float4* src = (const float4*)(conv_w + i);
    float4 a = src[0], c4 = src[1];
    int d = i >> 7, c0 = i & 127;
    int dch = d >> 6, dl = d & 63;
    uint4 w;
    w.x = f2bf2(a.x, a.y);   w.y = f2bf2(a.z, a.w);
    w.z = f2bf2(c4.x, c4.y); w.w = f2bf2(c4.z, c4.w);
    *(uint4*)((char*)Wsw + dch * 16384 + dl * 256 + ((c0 * 2) ^ swzr(dl))) = w;
  }
}

// ---------- mega-fused: xnorm + projection + logits/exp + vlad partials ----------
// Per block (n, 256-l chunk): 4 sub-chunks of 64 l. fT/eg never hit HBM.
//   e = exp(inv[l]*(M.x)[k][l] + bk[k]) -> etile LDS
//   f = inv[l]*(W.x)[d][l] + b          -> ftile LDS (d,l layout via swapped MFMA)
//   acc_v[k][d] += e[k][l] * f[d][l]    -> part (split-16 over l)
// LDS (124160 B, 1 block/CU):
//   Xsub 16K @0 | ftile 64K @16K | WsB 2x16K @80K | etile 8K @112K | invb/ps @120K
__global__ __launch_bounds__(512, 1) void k_fused(const float* __restrict__ x,
                                                  const unsigned short* __restrict__ Wsw,
                                                  const unsigned short* __restrict__ Mg,
                                                  const float* __restrict__ bk,
                                                  const float* __restrict__ conv_b,
                                                  float* __restrict__ part,
                                                  float* __restrict__ psums) {
  __shared__ __align__(16) char smem[124160];
  char* Xsub  = smem;                      // 64l x 256B: l*256 + ((c*2)^swzr(l))
  char* ftile = smem + 16384;              // 512d x 128B: d*128 + ((l*2)^swzr(d))
  char* WsB   = smem + 81920;              // 2 x (64d x 256B)
  char* etile = smem + 114688;             // 64k x 128B: k*128 + ((l*2)^swzr(k))
  float* invb = (float*)(smem + 122880);   // [64]
  float* ps   = (float*)(smem + 123136);   // [64][4]
  int n = blockIdx.y, lblk = blockIdx.x;
  int t = threadIdx.x, lane = t & 63, wid = t >> 6;
  int g2 = wid >> 2;                       // 2-way group (l for f-A, k for e/vlad)
  int g4 = wid & 3;                        // 4-way group (d for f-B/vlad, l for e)
  int r0 = (lane >> 4) << 2, cl = lane & 15;
  int hi8 = (lane >> 4) << 3;

  // block-invariant hoists: M A-frags, bk, conv_b per-dch scalar
  bfrag ma[4][2];
  #pragma unroll
  for (int kk = 0; kk < 4; kk++)
    #pragma unroll
    for (int m2 = 0; m2 < 2; m2++)
      ma[kk][m2] = *(const bfrag*)(Mg + (size_t)(g2 * 32 + m2 * 16 + cl) * CD + kk * 32 + hi8);
  float4 bkh[2];
  #pragma unroll
  for (int m2 = 0; m2 < 2; m2++) bkh[m2] = *(const float4*)(bk + g2 * 32 + m2 * 16 + r0);
  float bvh[8];
  #pragma unroll
  for (int dch = 0; dch < 8; dch++) bvh[dch] = conv_b[dch * 64 + g4 * 16 + cl];

  // prologue: stage Ws image 0 -> WsB[0]
  #pragma unroll
  for (int q = 0; q < 2; q++)
    gll16((const char*)Wsw + (q * 8 + wid) * 1024 + lane * 16, WsB + (q * 8 + wid) * 1024);

  facc zero = {0.f, 0.f, 0.f, 0.f};
  facc acc_v[2][8];
  #pragma unroll
  for (int m = 0; m < 2; m++)
    #pragma unroll
    for (int j = 0; j < 8; j++) acc_v[m][j] = zero;
  float rs[2][4] = {{0.f,0.f,0.f,0.f},{0.f,0.f,0.f,0.f}};

  for (int sub = 0; sub < 4; sub++) {
    int l0 = lblk * 256 + sub * 64;
    // P1: x fp32 (c-pair rows, 64 l) -> bf16 -> Xsub (l,c)
    {
      int c0 = (t >> 3) * 2;
      const float4* r0p = (const float4*)(x + ((size_t)n * CD + c0) * HW + l0);
      const float4* r1p = (const float4*)(x + ((size_t)n * CD + c0 + 1) * HW + l0);
      #pragma unroll
      for (int jj = 0; jj < 2; jj++) {
        int f4 = (t & 7) + 8 * jj;
        float4 a = r0p[f4], b = r1p[f4];
        int lb = f4 * 4;
        *(unsigned*)(Xsub + (lb + 0) * 256 + ((c0 * 2) ^ swzr(lb + 0))) = f2bf2(a.x, b.x);
        *(unsigned*)(Xsub + (lb + 1) * 256 + ((c0 * 2) ^ swzr(lb + 1))) = f2bf2(a.y, b.y);
        *(unsigned*)(Xsub + (lb + 2) * 256 + ((c0 * 2) ^ swzr(lb + 2))) = f2bf2(a.z, b.z);
        *(unsigned*)(Xsub + (lb + 3) * 256 + ((c0 * 2) ^ swzr(lb + 3))) = f2bf2(a.w, b.w);
      }
    }
    __syncthreads();                      // S1: Xsub ready; pending Ws stage drained
    // P2: inv[l] (8 threads/row)
    {
      int l = t >> 3;
      float ss = 0.f;
      #pragma unroll
      for (int p = 0; p < 2; p++) {
        int s16 = (t & 7) + 8 * p;
        bfrag v = *(const bfrag*)(Xsub + l * 256 + ((s16 * 16) ^ swzr(l)));
        #pragma unroll
        for (int i = 0; i < 8; i++) { float f = bf2f((unsigned short)v[i]); ss += f * f; }
      }
      ss += __shfl_xor(ss, 1); ss += __shfl_xor(ss, 2); ss += __shfl_xor(ss, 4);
      if ((t & 7) == 0) invb[l] = 1.0f / fmaxf(sqrtf(ss), 1e-12f);
    }
    __syncthreads();                      // S2: invb ready

    // per-sub hoists
    bfrag bfh[4][2];                      // f A-frags: rows g2*32 + m*16 + cl
    #pragma unroll
    for (int kk = 0; kk < 4; kk++)
      #pragma unroll
      for (int m = 0; m < 2; m++) {
        int row = g2 * 32 + m * 16 + cl;
        bfh[kk][m] = *(const bfrag*)(Xsub + row * 256 + (((kk * 32 + hi8) * 2) ^ swzr(row)));
      }
    float hinvq[2][4];
    #pragma unroll
    for (int m = 0; m < 2; m++)
      #pragma unroll
      for (int q = 0; q < 4; q++) hinvq[m][q] = invb[g2 * 32 + m * 16 + r0 + q];
    float invl = invb[g4 * 16 + cl];

    // e-MFMA: D[k][l] = M(64k x 128c) x Xsub(l-rows)^T
    facc e_acc[2];
    e_acc[0] = zero; e_acc[1] = zero;
    #pragma unroll
    for (int kk = 0; kk < 4; kk++) {
      int erow = g4 * 16 + cl;
      bfrag xe = *(const bfrag*)(Xsub + erow * 256 + (((kk * 32 + hi8) * 2) ^ swzr(erow)));
      #pragma unroll
      for (int m2 = 0; m2 < 2; m2++)
        e_acc[m2] = __builtin_amdgcn_mfma_f32_16x16x32_bf16(ma[kk][m2], xe, e_acc[m2], 0, 0, 0);
    }
    // e-epi: exp -> etile + rowsum partials
    #pragma unroll
    for (int m2 = 0; m2 < 2; m2++) {
      #pragma unroll
      for (int q = 0; q < 4; q++) {
        int k2 = g2 * 32 + m2 * 16 + r0 + q;
        float bkv = (q == 0) ? bkh[m2].x : (q == 1) ? bkh[m2].y : (q == 2) ? bkh[m2].z : bkh[m2].w;
        float ev = __expf(e_acc[m2][q] * invl + bkv);
        int l2 = g4 * 16 + cl;
        *(unsigned short*)(etile + k2 * 128 + ((l2 * 2) ^ swzr(k2))) = f2bf(ev);
        rs[m2][q] += ev;
      }
    }

    // f-loop: 8 d-chunks of 64; ftile(d,l) built in LDS; Ws double-buffered
    for (int dch = 0; dch < 8; dch++) {
      // stage next Ws image (wraps to 0 for next sub)
      {
        int nxt = (dch + 1) & 7;
        char* wdst = WsB + (((dch + 1) & 1) << 14);
        #pragma unroll
        for (int q = 0; q < 2; q++)
          gll16((const char*)Wsw + nxt * 16384 + (q * 8 + wid) * 1024 + lane * 16,
                wdst + (q * 8 + wid) * 1024);
      }
      const char* Wsb = WsB + ((dch & 1) << 14);
      // f-MFMA: D[l][d] (A=bfh l-frags, B=Ws d-frag), wave tile 32l x 16d
      facc fa[2];
      fa[0] = zero; fa[1] = zero;
      #pragma unroll
      for (int kk = 0; kk < 4; kk++) {
        int drow = g4 * 16 + cl;
        bfrag wf = *(const bfrag*)(Wsb + drow * 256 + (((kk * 32 + hi8) * 2) ^ swzr(drow)));
        #pragma unroll
        for (int m = 0; m < 2; m++)
          fa[m] = __builtin_amdgcn_mfma_f32_16x16x32_bf16(bfh[kk][m], wf, fa[m], 0, 0, 0);
      }
      // f-epi: f = inv[l]*acc + b -> ftile (quad spans l -> b64)
      {
        int d = dch * 64 + g4 * 16 + cl;
        float bv = bvh[dch];
        #pragma unroll
        for (int m = 0; m < 2; m++) {
          int lm = g2 * 32 + m * 16 + r0;
          uint2 w;
          w.x = f2bf2(fa[m][0] * hinvq[m][0] + bv, fa[m][1] * hinvq[m][1] + bv);
          w.y = f2bf2(fa[m][2] * hinvq[m][2] + bv, fa[m][3] * hinvq[m][3] + bv);
          *(uint2*)(ftile + d * 128 + ((lm * 2) ^ swzr(d))) = w;
        }
      }
      __syncthreads();                    // Ws(next) drained; ftile slice visible
    }

    // vlad-MFMA: acc_v[k][d] += etile(64k x 64l) x ftile(512d x 64l)^T
    #pragma unroll
    for (int kk2 = 0; kk2 < 2; kk2++) {
      int loff = (kk2 * 32 + hi8) * 2;
      bfrag ae[2];
      #pragma unroll
      for (int m = 0; m < 2; m++) {
        int krow = g2 * 32 + m * 16 + cl;
        ae[m] = *(const bfrag*)(etile + krow * 128 + (loff ^ swzr(krow)));
      }
      #pragma unroll
      for (int j = 0; j < 8; j++) {
        int d = g4 * 128 + j * 16 + cl;
        bfrag bf = *(const bfrag*)(ftile + d * 128 + (loff ^ swzr(d)));
        #pragma unroll
        for (int m = 0; m < 2; m++)
          acc_v[m][j] = __builtin_amdgcn_mfma_f32_16x16x32_bf16(ae[m], bf, acc_v[m][j], 0, 0, 0);
      }
    }
    __syncthreads();                      // etile/ftile reads done before next sub
  }

  // part write: (lblk, n, k, d) fp32
  {
    size_t base = ((size_t)(lblk * NB + n)) * (KC * DD);
    #pragma unroll
    for (int m = 0; m < 2; m++) {
      int krow = g2 * 32 + m * 16 + r0;
      #pragma unroll
      for (int j = 0; j < 8; j++) {
        int d = g4 * 128 + j * 16 + cl;
        #pragma unroll
        for (int q = 0; q < 4; q++)
          part[base + (size_t)(krow + q) * DD + d] = acc_v[m][j][q];
      }
    }
  }
  // psums: reduce rs over cl(16) then over g4 groups via ps
  #pragma unroll
  for (int m2 = 0; m2 < 2; m2++)
    #pragma unroll
    for (int q = 0; q < 4; q++) {
      float v = rs[m2][q];
      v += __shfl_xor(v, 1); v += __shfl_xor(v, 2);
      v += __shfl_xor(v, 4); v += __shfl_xor(v, 8);
      if (cl == 0) ps[(g2 * 32 + m2 * 16 + r0 + q) * 4 + g4] = v;
    }
  __syncthreads();
  if (t < 64) {
    float4 v = ((const float4*)ps)[t];
    psums[((size_t)n * 16 + lblk) * 64 + t] = v.x + v.y + v.z + v.w;
  }
}

// ---------- reduce split-16 partials, compute rinv inline, normalize ----------
__global__ __launch_bounds__(256) void k_reduce(const float* __restrict__ part,
                                                const float* __restrict__ psums,
                                                float* __restrict__ out) {
  int b = blockIdx.x, t = threadIdx.x;
  int nk = b >> 1;                              // constant per block
  int n = nk >> 6, k = nk & 63;
  __shared__ float rsh;
  if (t < 16) {
    float s = psums[((size_t)n * 16 + t) * 64 + k];
    s += __shfl_xor(s, 8, 16); s += __shfl_xor(s, 4, 16);
    s += __shfl_xor(s, 2, 16); s += __shfl_xor(s, 1, 16);
    if (t == 0) rsh = 1.0f / s;
  }
  __syncthreads();
  float rinv = rsh;
  int i = b * 256 + t;
  float s = 0.f;
  #pragma unroll
  for (int lc = 0; lc < 16; lc++) s += part[(size_t)lc * (NB * KC * DD) + i];
  out[i] = s * rinv;
}

extern "C" void kernel_launch(void* const* d_in, const int* in_sizes, int n_in,
                              void* d_out, int out_size, void* d_ws, size_t ws_size,
                              hipStream_t stream) {
  const float* x         = (const float*)d_in[0];
  const float* conv_w    = (const float*)d_in[1];
  const float* conv_b    = (const float*)d_in[2];
  const float* centroids = (const float*)d_in[3];
  float* out = (float*)d_out;
  char* ws = (char*)d_ws;

  // ws layout (bytes):
  //   Wsw   @ 0        (128 KB)   conv_w bf16, 8x16K pre-swizzled images
  //   Mg    @ 131072   (16 KB)    M = Cn.W bf16 (K,C)
  //   bk    @ 147456   (1 KB)     bk = Cn.b fp32 (K)
  //   psums @ 148480   (64 KB)    per-chunk row sums fp32 (N,16,K)
  //   part  @ 214016   (32 MB)    vlad partials fp32 (16,N,K,D)
  unsigned short* Wsw  = (unsigned short*)(ws);
  unsigned short* Mg   = (unsigned short*)(ws + 131072);
  float*          bk   = (float*)(ws + 147456);
  float*          psums= (float*)(ws + 148480);
  float*          part = (float*)(ws + 214016);

  k_prep<<<dim3(96), dim3(256), 0, stream>>>(conv_w, conv_b, centroids, Wsw, Mg, bk);

  // fused xnorm + projection + logits/exp + vlad partials (no fT/eg in HBM)
  k_fused<<<dim3(16, NB), dim3(512), 0, stream>>>(x, Wsw, Mg, bk, conv_b, part, psums);

  k_reduce<<<dim3(NB * KC * DD / 256), dim3(256), 0, stream>>>(part, psums, out);

  (void)in_sizes; (void)n_in; (void)out_size; (void)ws_size;
}

// Round 23
// 62.789 us; speedup vs baseline: 1.0415x; 1.0415x over previous
//
#include <hip/hip_runtime.h>

#define NB 16     // batch
#define CD 128    // channels
#define HW 4096   // spatial L
#define DD 512    // projected dim
#define KC 64     // clusters

typedef __attribute__((ext_vector_type(8))) short bfrag;           // 8 bf16 (4 VGPR)
typedef __attribute__((ext_vector_type(4))) float facc;            // MFMA acc

__device__ __forceinline__ unsigned short f2bf(float f) {
  union { float f; unsigned u; } v; v.f = f;
  unsigned r = v.u + 0x7fffu + ((v.u >> 16) & 1u);   // RNE
  return (unsigned short)(r >> 16);
}
__device__ __forceinline__ float bf2f(unsigned short h) {
  union { unsigned u; float f; } v; v.u = ((unsigned)h) << 16; return v.f;
}
// packed f32x2 -> bf16x2 (RNE), low16 = lo
__device__ __forceinline__ unsigned f2bf2(float lo, float hi) {
  unsigned r;
  asm("v_cvt_pk_bf16_f32 %0, %1, %2" : "=v"(r) : "v"(lo), "v"(hi));
  return r;
}
// async global->LDS: HW writes lds_base + lane*16; global src carries per-lane offset
__device__ __forceinline__ void gll16(const void* g, void* l) {
  __builtin_amdgcn_global_load_lds(
      (__attribute__((address_space(1))) void*)(uintptr_t)g,
      (__attribute__((address_space(3))) void*)(uintptr_t)l, 16, 0, 0);
}
// row swizzle: spreads row-parallel accesses across 8 16B slots
__device__ __forceinline__ int swzr(int r) { return ((r & 7) ^ ((r >> 3) & 7)) << 4; }

// ---------- prep (merged): M/bk rows (blocks 0..63) + Wsw images (blocks 64..95) ----------
// M[k][c] = inv_k * sum_d centroids[k][d]*W[d][c] (bf16); bk[k] = inv_k * (centroids[k].b)
// Wsw: 8 images x [64d x 256B], byte = dch*16384 + dl*256 + ((c*2)^swzr(dl))
__global__ __launch_bounds__(256) void k_prep(const float* __restrict__ conv_w,
                                              const float* __restrict__ conv_b,
                                              const float* __restrict__ centroids,
                                              unsigned short* __restrict__ Wsw,
                                              unsigned short* __restrict__ Mg,
                                              float* __restrict__ bk) {
  int b = blockIdx.x, t = threadIdx.x;
  if (b < KC) {
    __shared__ float red[4];
    __shared__ float sinv;
    __shared__ float mred[256];
    const float* row = centroids + (size_t)b * DD;
    float v0 = row[t], v1 = row[t + 256];
    float ss = v0 * v0 + v1 * v1;
    #pragma unroll
    for (int off = 32; off; off >>= 1) ss += __shfl_xor(ss, off);
    if ((t & 63) == 0) red[t >> 6] = ss;
    __syncthreads();
    if (t == 0) sinv = 1.0f / fmaxf(sqrtf(red[0] + red[1] + red[2] + red[3]), 1e-12f);
    __syncthreads();
    float inv = sinv;
    int dd = t >> 7, c = t & 127;
    float macc = 0.f;
    #pragma unroll 16
    for (int d0 = 0; d0 < DD; d0 += 2) {
      float cn = row[d0 + dd];
      macc += cn * conv_w[(size_t)(d0 + dd) * CD + c];
    }
    mred[t] = macc;
    float bp = v0 * conv_b[t] + v1 * conv_b[t + 256];
    #pragma unroll
    for (int off = 32; off; off >>= 1) bp += __shfl_xor(bp, off);
    if ((t & 63) == 0) red[t >> 6] = bp;
    __syncthreads();
    if (t < 128) Mg[(size_t)b * CD + t] = f2bf((mred[t] + mred[t + 128]) * inv);
    if (t == 0) bk[b] = (red[0] + red[1] + red[2] + red[3]) * inv;
  } else {
    int i = (b - KC) * 2048 + t * 8;            // 32 blocks cover 512x128
    const float4* src = (const float4*)(conv_w + i);
    float4 a = src[0], c4 = src[1];
    int d = i >> 7, c0 = i & 127;
    int dch = d >> 6, dl = d & 63;
    uint4 w;
    w.x = f2bf2(a.x, a.y);   w.y = f2bf2(a.z, a.w);
    w.z = f2bf2(c4.x, c4.y); w.w = f2bf2(c4.z, c4.w);
    *(uint4*)((char*)Wsw + dch * 16384 + dl * 256 + ((c0 * 2) ^ swzr(dl))) = w;
  }
}

// ---------- mega-fused: xnorm + projection + logits/exp + vlad partials ----------
// R23: no ma/bfh register hoists (VGPR < 128 cap, no spill); part writes row-coalesced.
// LDS (124160 B, 1 block/CU):
//   Xsub 16K @0 | ftile 64K @16K | WsB 2x16K @80K | etile 8K @112K | invb/ps @120K
__global__ __launch_bounds__(512, 1) void k_fused(const float* __restrict__ x,
                                                  const unsigned short* __restrict__ Wsw,
                                                  const unsigned short* __restrict__ Mg,
                                                  const float* __restrict__ bk,
                                                  const float* __restrict__ conv_b,
                                                  float* __restrict__ part,
                                                  float* __restrict__ psums) {
  __shared__ __align__(16) char smem[124160];
  char* Xsub  = smem;                      // 64l x 256B: l*256 + ((c*2)^swzr(l))
  char* ftile = smem + 16384;              // 512d x 128B: d*128 + ((l*2)^swzr(d))
  char* WsB   = smem + 81920;              // 2 x (64d x 256B)
  char* etile = smem + 114688;             // 64k x 128B: k*128 + ((l*2)^swzr(k))
  float* invb = (float*)(smem + 122880);   // [64]
  float* ps   = (float*)(smem + 123136);   // [64][4]
  int n = blockIdx.y, lblk = blockIdx.x;
  int t = threadIdx.x, lane = t & 63, wid = t >> 6;
  int g2 = wid >> 2;                       // 2-way group (l for f-A, k for e/vlad)
  int g4 = wid & 3;                        // 4-way group (d for f-B/vlad, l for e)
  int r0 = (lane >> 4) << 2, cl = lane & 15;
  int hi8 = (lane >> 4) << 3;

  float bvh[8];
  #pragma unroll
  for (int dch = 0; dch < 8; dch++) bvh[dch] = conv_b[dch * 64 + g4 * 16 + cl];

  // prologue: stage Ws image 0 -> WsB[0]
  #pragma unroll
  for (int q = 0; q < 2; q++)
    gll16((const char*)Wsw + (q * 8 + wid) * 1024 + lane * 16, WsB + (q * 8 + wid) * 1024);

  facc zero = {0.f, 0.f, 0.f, 0.f};
  facc acc_v[2][8];
  #pragma unroll
  for (int m = 0; m < 2; m++)
    #pragma unroll
    for (int j = 0; j < 8; j++) acc_v[m][j] = zero;
  float rs[2][4] = {{0.f,0.f,0.f,0.f},{0.f,0.f,0.f,0.f}};

  for (int sub = 0; sub < 4; sub++) {
    int l0 = lblk * 256 + sub * 64;
    // P1: x fp32 (c-pair rows, 64 l) -> bf16 -> Xsub (l,c)
    {
      int c0 = (t >> 3) * 2;
      const float4* r0p = (const float4*)(x + ((size_t)n * CD + c0) * HW + l0);
      const float4* r1p = (const float4*)(x + ((size_t)n * CD + c0 + 1) * HW + l0);
      #pragma unroll
      for (int jj = 0; jj < 2; jj++) {
        int f4 = (t & 7) + 8 * jj;
        float4 a = r0p[f4], b = r1p[f4];
        int lb = f4 * 4;
        *(unsigned*)(Xsub + (lb + 0) * 256 + ((c0 * 2) ^ swzr(lb + 0))) = f2bf2(a.x, b.x);
        *(unsigned*)(Xsub + (lb + 1) * 256 + ((c0 * 2) ^ swzr(lb + 1))) = f2bf2(a.y, b.y);
        *(unsigned*)(Xsub + (lb + 2) * 256 + ((c0 * 2) ^ swzr(lb + 2))) = f2bf2(a.z, b.z);
        *(unsigned*)(Xsub + (lb + 3) * 256 + ((c0 * 2) ^ swzr(lb + 3))) = f2bf2(a.w, b.w);
      }
    }
    __syncthreads();                      // S1: Xsub ready; pending Ws stage drained
    // P2: inv[l] (8 threads/row)
    {
      int l = t >> 3;
      float ss = 0.f;
      #pragma unroll
      for (int p = 0; p < 2; p++) {
        int s16 = (t & 7) + 8 * p;
        bfrag v = *(const bfrag*)(Xsub + l * 256 + ((s16 * 16) ^ swzr(l)));
        #pragma unroll
        for (int i = 0; i < 8; i++) { float f = bf2f((unsigned short)v[i]); ss += f * f; }
      }
      ss += __shfl_xor(ss, 1); ss += __shfl_xor(ss, 2); ss += __shfl_xor(ss, 4);
      if ((t & 7) == 0) invb[l] = 1.0f / fmaxf(sqrtf(ss), 1e-12f);
    }
    __syncthreads();                      // S2: invb ready

    float hinvq[2][4];
    #pragma unroll
    for (int m = 0; m < 2; m++)
      #pragma unroll
      for (int q = 0; q < 4; q++) hinvq[m][q] = invb[g2 * 32 + m * 16 + r0 + q];
    float invl = invb[g4 * 16 + cl];

    // e-MFMA: D[k][l] = M(64k x 128c) x Xsub(l-rows)^T  (M frags from L2)
    facc e_acc[2];
    e_acc[0] = zero; e_acc[1] = zero;
    #pragma unroll
    for (int kk = 0; kk < 4; kk++) {
      int erow = g4 * 16 + cl;
      bfrag xe = *(const bfrag*)(Xsub + erow * 256 + (((kk * 32 + hi8) * 2) ^ swzr(erow)));
      #pragma unroll
      for (int m2 = 0; m2 < 2; m2++) {
        bfrag mafr = *(const bfrag*)(Mg + (size_t)(g2 * 32 + m2 * 16 + cl) * CD + kk * 32 + hi8);
        e_acc[m2] = __builtin_amdgcn_mfma_f32_16x16x32_bf16(mafr, xe, e_acc[m2], 0, 0, 0);
      }
    }
    // e-epi: exp -> etile + rowsum partials
    #pragma unroll
    for (int m2 = 0; m2 < 2; m2++) {
      int k20 = g2 * 32 + m2 * 16 + r0;
      float4 bkq = *(const float4*)(bk + k20);
      #pragma unroll
      for (int q = 0; q < 4; q++) {
        int k2 = k20 + q;
        float bkv = (q == 0) ? bkq.x : (q == 1) ? bkq.y : (q == 2) ? bkq.z : bkq.w;
        float ev = __expf(e_acc[m2][q] * invl + bkv);
        int l2 = g4 * 16 + cl;
        *(unsigned short*)(etile + k2 * 128 + ((l2 * 2) ^ swzr(k2))) = f2bf(ev);
        rs[m2][q] += ev;
      }
    }

    // f-loop: 8 d-chunks of 64; ftile(d,l) built in LDS; Ws double-buffered
    for (int dch = 0; dch < 8; dch++) {
      // stage next Ws image (wraps to 0 for next sub)
      {
        int nxt = (dch + 1) & 7;
        char* wdst = WsB + (((dch + 1) & 1) << 14);
        #pragma unroll
        for (int q = 0; q < 2; q++)
          gll16((const char*)Wsw + nxt * 16384 + (q * 8 + wid) * 1024 + lane * 16,
                wdst + (q * 8 + wid) * 1024);
      }
      const char* Wsb = WsB + ((dch & 1) << 14);
      // f-MFMA: D[l][d] (A = Xsub l-frags from LDS, B = Ws d-frag), wave 32l x 16d
      facc fa[2];
      fa[0] = zero; fa[1] = zero;
      #pragma unroll
      for (int kk = 0; kk < 4; kk++) {
        int drow = g4 * 16 + cl;
        bfrag wf = *(const bfrag*)(Wsb + drow * 256 + (((kk * 32 + hi8) * 2) ^ swzr(drow)));
        #pragma unroll
        for (int m = 0; m < 2; m++) {
          int row = g2 * 32 + m * 16 + cl;
          bfrag xa = *(const bfrag*)(Xsub + row * 256 + (((kk * 32 + hi8) * 2) ^ swzr(row)));
          fa[m] = __builtin_amdgcn_mfma_f32_16x16x32_bf16(xa, wf, fa[m], 0, 0, 0);
        }
      }
      // f-epi: f = inv[l]*acc + b -> ftile (quad spans l -> b64)
      {
        int d = dch * 64 + g4 * 16 + cl;
        float bv = bvh[dch];
        #pragma unroll
        for (int m = 0; m < 2; m++) {
          int lm = g2 * 32 + m * 16 + r0;
          uint2 w;
          w.x = f2bf2(fa[m][0] * hinvq[m][0] + bv, fa[m][1] * hinvq[m][1] + bv);
          w.y = f2bf2(fa[m][2] * hinvq[m][2] + bv, fa[m][3] * hinvq[m][3] + bv);
          *(uint2*)(ftile + d * 128 + ((lm * 2) ^ swzr(d))) = w;
        }
      }
      __syncthreads();                    // Ws(next) drained; ftile slice visible
    }

    // vlad-MFMA: acc_v[k][d] += etile(64k x 64l) x ftile(512d x 64l)^T
    #pragma unroll
    for (int kk2 = 0; kk2 < 2; kk2++) {
      int loff = (kk2 * 32 + hi8) * 2;
      bfrag ae[2];
      #pragma unroll
      for (int m = 0; m < 2; m++) {
        int krow = g2 * 32 + m * 16 + cl;
        ae[m] = *(const bfrag*)(etile + krow * 128 + (loff ^ swzr(krow)));
      }
      #pragma unroll
      for (int j = 0; j < 8; j++) {
        int d = g4 * 128 + j * 16 + cl;
        bfrag bf = *(const bfrag*)(ftile + d * 128 + (loff ^ swzr(d)));
        #pragma unroll
        for (int m = 0; m < 2; m++)
          acc_v[m][j] = __builtin_amdgcn_mfma_f32_16x16x32_bf16(ae[m], bf, acc_v[m][j], 0, 0, 0);
      }
    }
    __syncthreads();                      // etile/ftile reads done before next sub
  }

  // part write: (lblk, n, k, d) fp32 — row-major, j innermost for full-line coalescing
  {
    size_t base = ((size_t)(lblk * NB + n)) * (KC * DD);
    #pragma unroll
    for (int m = 0; m < 2; m++) {
      #pragma unroll
      for (int q = 0; q < 4; q++) {
        int krow = g2 * 32 + m * 16 + r0 + q;
        float* rowp = part + base + (size_t)krow * DD + g4 * 128;
        #pragma unroll
        for (int j = 0; j < 8; j++)
          rowp[j * 16 + cl] = acc_v[m][j][q];
      }
    }
  }
  // psums: reduce rs over cl(16) then over g4 groups via ps
  #pragma unroll
  for (int m2 = 0; m2 < 2; m2++)
    #pragma unroll
    for (int q = 0; q < 4; q++) {
      float v = rs[m2][q];
      v += __shfl_xor(v, 1); v += __shfl_xor(v, 2);
      v += __shfl_xor(v, 4); v += __shfl_xor(v, 8);
      if (cl == 0) ps[(g2 * 32 + m2 * 16 + r0 + q) * 4 + g4] = v;
    }
  __syncthreads();
  if (t < 64) {
    float4 v = ((const float4*)ps)[t];
    psums[((size_t)n * 16 + lblk) * 64 + t] = v.x + v.y + v.z + v.w;
  }
}

// ---------- reduce split-16 partials, compute rinv inline, normalize ----------
__global__ __launch_bounds__(256) void k_reduce(const float* __restrict__ part,
                                                const float* __restrict__ psums,
                                                float* __restrict__ out) {
  int b = blockIdx.x, t = threadIdx.x;
  int nk = b >> 1;                              // constant per block
  int n = nk >> 6, k = nk & 63;
  __shared__ float rsh;
  if (t < 16) {
    float s = psums[((size_t)n * 16 + t) * 64 + k];
    s += __shfl_xor(s, 8, 16); s += __shfl_xor(s, 4, 16);
    s += __shfl_xor(s, 2, 16); s += __shfl_xor(s, 1, 16);
    if (t == 0) rsh = 1.0f / s;
  }
  __syncthreads();
  float rinv = rsh;
  int i = b * 256 + t;
  float s = 0.f;
  #pragma unroll
  for (int lc = 0; lc < 16; lc++) s += part[(size_t)lc * (NB * KC * DD) + i];
  out[i] = s * rinv;
}

extern "C" void kernel_launch(void* const* d_in, const int* in_sizes, int n_in,
                              void* d_out, int out_size, void* d_ws, size_t ws_size,
                              hipStream_t stream) {
  const float* x         = (const float*)d_in[0];
  const float* conv_w    = (const float*)d_in[1];
  const float* conv_b    = (const float*)d_in[2];
  const float* centroids = (const float*)d_in[3];
  float* out = (float*)d_out;
  char* ws = (char*)d_ws;

  // ws layout (bytes):
  //   Wsw   @ 0        (128 KB)   conv_w bf16, 8x16K pre-swizzled images
  //   Mg    @ 131072   (16 KB)    M = Cn.W bf16 (K,C)
  //   bk    @ 147456   (1 KB)     bk = Cn.b fp32 (K)
  //   psums @ 148480   (64 KB)    per-chunk row sums fp32 (N,16,K)
  //   part  @ 214016   (32 MB)    vlad partials fp32 (16,N,K,D)
  unsigned short* Wsw  = (unsigned short*)(ws);
  unsigned short* Mg   = (unsigned short*)(ws + 131072);
  float*          bk   = (float*)(ws + 147456);
  float*          psums= (float*)(ws + 148480);
  float*          part = (float*)(ws + 214016);

  k_prep<<<dim3(96), dim3(256), 0, stream>>>(conv_w, conv_b, centroids, Wsw, Mg, bk);

  // fused xnorm + projection + logits/exp + vlad partials (no fT/eg in HBM)
  k_fused<<<dim3(16, NB), dim3(512), 0, stream>>>(x, Wsw, Mg, bk, conv_b, part, psums);

  k_reduce<<<dim3(NB * KC * DD / 256), dim3(256), 0, stream>>>(part, psums, out);

  (void)in_sizes; (void)n_in; (void)out_size; (void)ws_size;
}

// Round 24
// 54.811 us; speedup vs baseline: 1.1931x; 1.1456x over previous
//
#include <hip/hip_runtime.h>

#define NB 16     // batch
#define CD 128    // channels
#define HW 4096   // spatial L
#define DD 512    // projected dim
#define KC 64     // clusters

typedef __attribute__((ext_vector_type(8))) short bfrag;           // 8 bf16 (4 VGPR)
typedef __attribute__((ext_vector_type(4))) float facc;            // MFMA acc

__device__ __forceinline__ unsigned short f2bf(float f) {
  union { float f; unsigned u; } v; v.f = f;
  unsigned r = v.u + 0x7fffu + ((v.u >> 16) & 1u);   // RNE
  return (unsigned short)(r >> 16);
}
__device__ __forceinline__ float bf2f(unsigned short h) {
  union { unsigned u; float f; } v; v.u = ((unsigned)h) << 16; return v.f;
}
// packed f32x2 -> bf16x2 (RNE), low16 = lo
__device__ __forceinline__ unsigned f2bf2(float lo, float hi) {
  unsigned r;
  asm("v_cvt_pk_bf16_f32 %0, %1, %2" : "=v"(r) : "v"(lo), "v"(hi));
  return r;
}
// async global->LDS: HW writes lds_base + lane*16; global src carries per-lane offset
__device__ __forceinline__ void gll16(const void* g, void* l) {
  __builtin_amdgcn_global_load_lds(
      (__attribute__((address_space(1))) void*)(uintptr_t)g,
      (__attribute__((address_space(3))) void*)(uintptr_t)l, 16, 0, 0);
}
// row swizzle: spreads row-parallel accesses across 8 16B slots
__device__ __forceinline__ int swzr(int r) { return ((r & 7) ^ ((r >> 3) & 7)) << 4; }

// ---------- prep: pre-swizzled W / normalized-centroid LDS images ----------
// Wsw:  8 images x [64d x 256B], byte = dch*16384 + dl*256 + ((c*2)^swzr(dl))
// Cbsw: 8 images x [64k x 128B], byte = dch*8192  + k*128  + ((dl*2)^swzr(k))
__global__ __launch_bounds__(256) void k_prep(const float* __restrict__ conv_w,
                                              const float* __restrict__ centroids,
                                              unsigned short* __restrict__ Wsw,
                                              unsigned short* __restrict__ Cbsw) {
  int b = blockIdx.x, t = threadIdx.x;
  if (b < KC) {
    const float* row = centroids + (size_t)b * DD;
    float v0 = row[t], v1 = row[t + 256];
    float ss = v0 * v0 + v1 * v1;
    #pragma unroll
    for (int off = 32; off; off >>= 1) ss += __shfl_xor(ss, off);
    __shared__ float red[4];
    if ((t & 63) == 0) red[t >> 6] = ss;
    __syncthreads();
    float tot = red[0] + red[1] + red[2] + red[3];
    float inv = 1.0f / fmaxf(sqrtf(tot), 1e-12f);
    int d0 = t, d1 = t + 256;
    *(unsigned short*)((char*)Cbsw + (d0 >> 6) * 8192 + b * 128 +
                       (((d0 & 63) * 2) ^ swzr(b))) = f2bf(v0 * inv);
    *(unsigned short*)((char*)Cbsw + (d1 >> 6) * 8192 + b * 128 +
                       (((d1 & 63) * 2) ^ swzr(b))) = f2bf(v1 * inv);
  } else {
    int i = (b - KC) * 2048 + t * 8;            // 32 blocks cover 512x128
    const float4* src = (const float4*)(conv_w + i);
    float4 a = src[0], c4 = src[1];
    int d = i >> 7, c0 = i & 127;
    int dch = d >> 6, dl = d & 63;
    uint4 w;
    w.x = f2bf2(a.x, a.y);   w.y = f2bf2(a.z, a.w);
    w.z = f2bf2(c4.x, c4.y); w.w = f2bf2(c4.z, c4.w);
    *(uint4*)((char*)Wsw + dch * 16384 + dl * 256 + ((c0 * 2) ^ swzr(dl))) = w;
  }
}

// ---------- fused xnorm + projection + logits/exp — counted-vmcnt loop (R18) ----------
__global__ __launch_bounds__(512, 2) void k_xproj(const float* __restrict__ x,
                                                  const unsigned short* __restrict__ Wsw,
                                                  const unsigned short* __restrict__ Cbsw,
                                                  const float* __restrict__ conv_b,
                                                  unsigned short* __restrict__ fT,
                                                  unsigned short* __restrict__ eg,
                                                  float* __restrict__ psums) {
  __shared__ __align__(16) char smem[67072];
  char* Xraw  = smem;                     // 128l x 256B: l*256 + ((c*2)^swzr(l))
  char* fbuf  = smem;                     // 128l x 128B (aliases Xraw lo, dead after hoist)
  char* etile = smem + 16384;             // aliases Xraw hi
  char* Ws    = smem + 32768;             // 64d x 256B
  char* Cb2   = smem + 49152;             // 2 x (64k x 128B)
  float* invb = (float*)(smem + 65536);   // [128]
  float* ps   = (float*)(smem + 66048);   // [64][4]
  int n = blockIdx.y, lblk = blockIdx.x, l0 = lblk * 128;
  int t = threadIdx.x, lane = t & 63, wid = t >> 6;

  // prologue: stage Ws(0) + Cbs(0)->buf0 (drained at B-P1's full syncthreads)
  #pragma unroll
  for (int q = 0; q < 2; q++)
    gll16((const char*)Wsw + (q * 8 + wid) * 1024 + lane * 16, Ws + (q * 8 + wid) * 1024);
  gll16((const char*)Cbsw + wid * 1024 + lane * 16, Cb2 + wid * 1024);

  // P1: x fp32 (c-pair rows) -> bf16 -> Xraw (l,c), u32 pair-writes
  #pragma unroll
  for (int j = 0; j < 2; j++) {
    int c0 = ((t >> 4) + 32 * j) * 2;
    const float4* r0p = (const float4*)(x + ((size_t)n * CD + c0) * HW + l0);
    const float4* r1p = (const float4*)(x + ((size_t)n * CD + c0 + 1) * HW + l0);
    #pragma unroll
    for (int jj = 0; jj < 2; jj++) {
      int f4 = (t & 15) + 16 * jj;
      float4 a = r0p[f4], b = r1p[f4];
      int lb = f4 * 4;
      *(unsigned*)(Xraw + (lb + 0) * 256 + ((c0 * 2) ^ swzr(lb + 0))) = f2bf2(a.x, b.x);
      *(unsigned*)(Xraw + (lb + 1) * 256 + ((c0 * 2) ^ swzr(lb + 1))) = f2bf2(a.y, b.y);
      *(unsigned*)(Xraw + (lb + 2) * 256 + ((c0 * 2) ^ swzr(lb + 2))) = f2bf2(a.z, b.z);
      *(unsigned*)(Xraw + (lb + 3) * 256 + ((c0 * 2) ^ swzr(lb + 3))) = f2bf2(a.w, b.w);
    }
  }
  __syncthreads();                        // B-P1 (full drain): Xraw ready; stage(0) done

  // P2: inv[l] from row sums (b128 reads; XOR permutation is sum-invariant)
  {
    int l = t >> 2;
    float ss = 0.f;
    #pragma unroll
    for (int p = 0; p < 4; p++) {
      int s16 = (t & 3) + 4 * p;
      bfrag v = *(const bfrag*)(Xraw + l * 256 + ((s16 * 16) ^ swzr(l)));
      #pragma unroll
      for (int i = 0; i < 8; i++) { float f = bf2f((unsigned short)v[i]); ss += f * f; }
    }
    ss += __shfl_xor(ss, 1); ss += __shfl_xor(ss, 2);
    if ((t & 3) == 0) invb[l] = 1.0f / fmaxf(sqrtf(ss), 1e-12f);
  }
  __syncthreads();                        // B-P2: invb ready

  int wd = wid & 1, wl = wid >> 1;        // f waves: 2(d-grp of 32) x 4(l-grp of 32)
  int er = wid >> 2, ec = wid & 3;        // e waves: 2(k-grp of 32) x 4(l-grp of 32)
  int r0 = (lane >> 4) << 2, cl = lane & 15;
  int hi8 = (lane >> 4) << 3;

  // hoist Xraw B-fragments (dch-invariant, 32 VGPR) + per-l-frag inv
  bfrag bfh[4][2];
  #pragma unroll
  for (int kk = 0; kk < 4; kk++)
    #pragma unroll
    for (int j = 0; j < 2; j++) {
      int row = wl * 32 + j * 16 + cl;
      int c0e = kk * 32 + hi8;
      bfh[kk][j] = *(const bfrag*)(Xraw + row * 256 + ((c0e * 2) ^ swzr(row)));
    }
  float hinv[2];
  #pragma unroll
  for (int j = 0; j < 2; j++) hinv[j] = invb[wl * 32 + j * 16 + cl];
  __syncthreads();                        // B-H: Xraw dead -> fbuf/etile usable; queue empty

  facc zero = {0.f, 0.f, 0.f, 0.f};
  facc e_acc[2][2];
  e_acc[0][0] = zero; e_acc[0][1] = zero; e_acc[1][0] = zero; e_acc[1][1] = zero;

  for (int dch = 0; dch < 8; dch++) {
    const char* Cbs = Cb2 + ((dch & 1) << 13);
    // f-MFMA: D[d][l], wave tile 32d x 32l
    facc acc[2][2];
    acc[0][0] = zero; acc[0][1] = zero; acc[1][0] = zero; acc[1][1] = zero;
    #pragma unroll
    for (int kk = 0; kk < 4; kk++) {
      int c0e = kk * 32 + hi8;
      bfrag am[2];
      #pragma unroll
      for (int m = 0; m < 2; m++) {
        int d = wd * 32 + m * 16 + cl;
        am[m] = *(const bfrag*)(Ws + d * 256 + ((c0e * 2) ^ swzr(d)));
      }
      #pragma unroll
      for (int m = 0; m < 2; m++)
        #pragma unroll
        for (int j = 0; j < 2; j++)
          acc[m][j] = __builtin_amdgcn_mfma_f32_16x16x32_bf16(am[m], bfh[kk][j], acc[m][j], 0, 0, 0);
    }
    // epilogue: f = inv[l]*acc + bias -> fbuf(l,d64); quad spans d -> b64 writes
    #pragma unroll
    for (int m = 0; m < 2; m++) {
      int d0 = wd * 32 + m * 16 + r0;
      float4 bq = *(const float4*)(conv_b + dch * 64 + d0);
      #pragma unroll
      for (int j = 0; j < 2; j++) {
        int l = wl * 32 + j * 16 + cl;
        uint2 w;
        w.x = f2bf2(acc[m][j][0] * hinv[j] + bq.x, acc[m][j][1] * hinv[j] + bq.y);
        w.y = f2bf2(acc[m][j][2] * hinv[j] + bq.z, acc[m][j][3] * hinv[j] + bq.w);
        *(uint2*)(fbuf + l * 128 + ((d0 * 2) ^ swzr(l))) = w;
      }
    }
    // B_mid: Cbs(dch) drained + fbuf visible; old stores stay in flight
    asm volatile("s_waitcnt vmcnt(2) lgkmcnt(0)" ::: "memory");
    __builtin_amdgcn_s_barrier();
    __builtin_amdgcn_sched_barrier(0);
    // stage Ws(dch+1) + Cbs(dch+1) (issue order pinned: stages before stores)
    if (dch < 7) {
      #pragma unroll
      for (int q = 0; q < 2; q++)
        gll16((const char*)Wsw + (dch + 1) * 16384 + (q * 8 + wid) * 1024 + lane * 16,
              Ws + (q * 8 + wid) * 1024);
      gll16((const char*)Cbsw + (dch + 1) * 8192 + wid * 1024 + lane * 16,
            Cb2 + (((dch + 1) & 1) << 13) + wid * 1024);
    }
    __builtin_amdgcn_sched_barrier(0);
    // coalesced fT dump (2 b128 ds_reads + 2 global stores; stores drain next iter)
    {
      #pragma unroll
      for (int p = 0; p < 2; p++) {
        int ch = p * 512 + t;
        int lr = ch >> 3, c16 = ch & 7;
        bfrag v = *(const bfrag*)(fbuf + lr * 128 + ((c16 * 16) ^ swzr(lr)));
        *(bfrag*)(fT + ((size_t)n * HW + l0 + lr) * DD + dch * 64 + c16 * 8) = v;
      }
    }
    // e-MFMA: e_acc += Cbs(64k x 64d) x fbuf(128l x 64d)^T, wave tile 32k x 32l
    #pragma unroll
    for (int kk = 0; kk < 2; kk++) {
      int d0 = kk * 32 + hi8;
      bfrag ca[2], fb[2];
      #pragma unroll
      for (int m2 = 0; m2 < 2; m2++) {
        int k2 = er * 32 + m2 * 16 + cl;
        ca[m2] = *(const bfrag*)(Cbs + k2 * 128 + ((d0 * 2) ^ swzr(k2)));
      }
      #pragma unroll
      for (int j2 = 0; j2 < 2; j2++) {
        int l2 = ec * 32 + j2 * 16 + cl;
        fb[j2] = *(const bfrag*)(fbuf + l2 * 128 + ((d0 * 2) ^ swzr(l2)));
      }
      #pragma unroll
      for (int m2 = 0; m2 < 2; m2++)
        #pragma unroll
        for (int j2 = 0; j2 < 2; j2++)
          e_acc[m2][j2] = __builtin_amdgcn_mfma_f32_16x16x32_bf16(ca[m2], fb[j2], e_acc[m2][j2], 0, 0, 0);
    }
    // B_top: fbuf reads done; Ws(dch+1) drained; stores from this iter stay
    asm volatile("s_waitcnt vmcnt(3) lgkmcnt(0)" ::: "memory");
    __builtin_amdgcn_s_barrier();
    __builtin_amdgcn_sched_barrier(0);
  }

  // P5: exp -> etile + rowsum partials
  {
    int l2base = ec * 32;
    #pragma unroll
    for (int m2 = 0; m2 < 2; m2++) {
      #pragma unroll
      for (int q = 0; q < 4; q++) {
        int k2 = er * 32 + m2 * 16 + r0 + q;
        float vsum = 0.f;
        #pragma unroll
        for (int j2 = 0; j2 < 2; j2++) {
          int l2 = l2base + j2 * 16 + cl;
          float ev = __expf(e_acc[m2][j2][q]);
          *(unsigned short*)(etile + (l2 >> 6) * 8192 + k2 * 128 +
                             (((l2 & 63) * 2) ^ swzr(k2))) = f2bf(ev);
          vsum += ev;
        }
        vsum += __shfl_xor(vsum, 1); vsum += __shfl_xor(vsum, 2);
        vsum += __shfl_xor(vsum, 4); vsum += __shfl_xor(vsum, 8);
        if (cl == 0) ps[k2 * 4 + ec] = vsum;
      }
    }
  }
  __syncthreads();                        // full drain before final dumps
  // dump 2 e-images (16K contiguous) + psums
  {
    size_t base = ((size_t)n * 64 + lblk * 2) * 8192;
    #pragma unroll
    for (int p = 0; p < 2; p++) {
      uint4 v = *(const uint4*)(etile + (t + p * 512) * 16);
      *(uint4*)((char*)eg + base + (t + p * 512) * 16) = v;
    }
  }
  if (t < 64) {
    float4 v = ((const float4*)ps)[t];
    psums[((size_t)n * 32 + lblk) * 64 + t] = v.x + v.y + v.z + v.w;
  }
}

// ---------- vlad partials: part[sk,n,k,d] = sum_l e[n,k,l] f[n,l,d] ----------
// split-L 8 (grid 512, 2 blocks/CU), reg-prefetch of fT B-tile, counted-vmcnt.
__global__ __launch_bounds__(256, 2) void k_vlad(const unsigned short* __restrict__ eg,
                                                 const unsigned short* __restrict__ fT,
                                                 float* __restrict__ part) {
  __shared__ __align__(16) char smem[49152];
  char* As = smem;            // 2 images x [64k x 128B]: k*128 + ((l''*2)^swzr(k))
  char* Bs = smem + 16384;    // [128d][128l]: d*256 + ((l*2)^(((d&7)^((d>>3)&7))<<4))
  int t = threadIdx.x, lane = t & 63, wid = t >> 6;
  int wr = wid >> 1, wc = wid & 1;
  int lin = blockIdx.x;
  int xcd = lin & 7, jj = lin >> 3;                // jj 0..63
  int grp = xcd * 16 + (jj >> 2);                  // 0..127 = (n,sk)
  int dt = jj & 3, n = grp >> 3, sk = grp & 7;
  int dbase = dt * 128;
  const unsigned short* fTb = fT + (size_t)n * HW * DD + dbase;
  facc acc[2][4];
  facc zero = {0.f, 0.f, 0.f, 0.f};
  #pragma unroll
  for (int m = 0; m < 2; m++)
    #pragma unroll
    for (int j = 0; j < 4; j++) acc[m][j] = zero;

  // prologue: prefetch B(0) into regs (latency exposed once)
  bfrag br[8];
  #pragma unroll
  for (int q = 0; q < 8; q++) {
    int ch = q * 256 + t;
    int l = ch >> 4, dc = ch & 15;
    br[q] = *(const bfrag*)(fTb + (size_t)(sk * 512 + l) * DD + dc * 8);
  }

  #pragma unroll
  for (int ks = 0; ks < 4; ks++) {
    int l0 = sk * 512 + ks * 128;
    // write Breg -> Bs (auto-waits on br loads: issued one iteration ago)
    #pragma unroll
    for (int q = 0; q < 8; q++) {
      int ch = q * 256 + t;
      int l = ch >> 4, dc = ch & 15;
      #pragma unroll
      for (int i = 0; i < 8; i++) {
        int d = dc * 8 + i;
        int swz = (((d & 7) ^ ((d >> 3) & 7)) << 4);
        *(unsigned short*)(Bs + d * 256 + ((l * 2) ^ swz)) = (unsigned short)br[q][i];
      }
    }
    __builtin_amdgcn_sched_barrier(0);
    // issue gll16 A(ks): two consecutive 8K e-images for this l-range
    {
      const char* easrc = (const char*)eg + ((size_t)n * 64 + (l0 >> 6)) * 8192;
      #pragma unroll
      for (int q = 0; q < 4; q++)
        gll16(easrc + (q * 4 + wid) * 1024 + lane * 16, As + (q * 4 + wid) * 1024);
    }
    __builtin_amdgcn_sched_barrier(0);
    // prefetch B(ks+1) (stays in flight across the mid barrier)
    if (ks < 3) {
      #pragma unroll
      for (int q = 0; q < 8; q++) {
        int ch = q * 256 + t;
        int l = ch >> 4, dc = ch & 15;
        br[q] = *(const bfrag*)(fTb + (size_t)(l0 + 128 + l) * DD + dc * 8);
      }
      asm volatile("s_waitcnt vmcnt(8) lgkmcnt(0)" ::: "memory");   // drain A, keep B'
    } else {
      asm volatile("s_waitcnt vmcnt(0) lgkmcnt(0)" ::: "memory");   // last iter: drain all
    }
    __builtin_amdgcn_s_barrier();
    __builtin_amdgcn_sched_barrier(0);
    // MFMA over As (2 images) x Bs
    #pragma unroll
    for (int kk = 0; kk < 128; kk += 32) {
      int lk = kk + ((lane >> 4) << 3);
      const char* Ai = As + (kk >> 6) * 8192;
      int ll = lk & 63;
      bfrag af[2], bf[4];
      #pragma unroll
      for (int m = 0; m < 2; m++) {
        int krow = wr * 32 + m * 16 + (lane & 15);
        af[m] = *(const bfrag*)(Ai + krow * 128 + ((ll * 2) ^ swzr(krow)));
      }
      #pragma unroll
      for (int j = 0; j < 4; j++) {
        int d = wc * 64 + j * 16 + (lane & 15);
        int swz = (((d & 7) ^ ((d >> 3) & 7)) << 4);
        bf[j] = *(const bfrag*)(Bs + d * 256 + ((lk * 2) ^ swz));
      }
      #pragma unroll
      for (int m = 0; m < 2; m++)
        #pragma unroll
        for (int j = 0; j < 4; j++)
          acc[m][j] = __builtin_amdgcn_mfma_f32_16x16x32_bf16(af[m], bf[j], acc[m][j], 0, 0, 0);
    }
    // end barrier: LDS reads done; B' stays in flight
    asm volatile("s_waitcnt lgkmcnt(0)" ::: "memory");
    __builtin_amdgcn_s_barrier();
    __builtin_amdgcn_sched_barrier(0);
  }
  int r0 = (lane >> 4) << 2, cl = lane & 15;
  size_t base = ((size_t)(sk * NB + n)) * (KC * DD);
  #pragma unroll
  for (int m = 0; m < 2; m++) {
    int krow = wr * 32 + m * 16 + r0;
    #pragma unroll
    for (int j = 0; j < 4; j++) {
      int d = dbase + wc * 64 + j * 16 + cl;
      #pragma unroll
      for (int q = 0; q < 4; q++)
        part[base + (size_t)(krow + q) * DD + d] = acc[m][j][q];
    }
  }
}

// ---------- reduce split-K partials (8), compute rinv inline, normalize ----------
__global__ __launch_bounds__(256) void k_reduce(const float* __restrict__ part,
                                                const float* __restrict__ psums,
                                                float* __restrict__ out) {
  int b = blockIdx.x, t = threadIdx.x;
  int nk = b >> 1;                              // constant per block
  int n = nk >> 6, k = nk & 63;
  __shared__ float rsh;
  if (t < 32) {
    float s = psums[((size_t)n * 32 + t) * 64 + k];
    #pragma unroll
    for (int off = 16; off; off >>= 1) s += __shfl_xor(s, off, 32);
    if (t == 0) rsh = 1.0f / s;
  }
  __syncthreads();
  float rinv = rsh;
  int i = b * 256 + t;
  float s = 0.f;
  #pragma unroll
  for (int skk = 0; skk < 8; skk++) s += part[(size_t)skk * (NB * KC * DD) + i];
  out[i] = s * rinv;
}

extern "C" void kernel_launch(void* const* d_in, const int* in_sizes, int n_in,
                              void* d_out, int out_size, void* d_ws, size_t ws_size,
                              hipStream_t stream) {
  const float* x         = (const float*)d_in[0];
  const float* conv_w    = (const float*)d_in[1];
  const float* conv_b    = (const float*)d_in[2];
  const float* centroids = (const float*)d_in[3];
  float* out = (float*)d_out;
  char* ws = (char*)d_ws;

  // ws layout (bytes):
  //   Wsw   @ 0          (128 KB)   conv_w bf16, 8x16K pre-swizzled images
  //   Cbsw  @ 131072     (64 KB)    normalized centroids bf16, 8x8K images
  //   fT    @ 196608     (64 MB)    f bf16 (N,L,D)
  //   eg    @ 67305472   (8 MB)     exp(logits) bf16, N*64 x 8K images
  //   psums @ 75694080   (128 KB)   per-tile row sums fp32 (N,32,K)
  //   part  @ 75960320   (16 MB)    vlad partials fp32 (8,N,K,D)
  unsigned short* Wsw  = (unsigned short*)(ws);
  unsigned short* Cbsw = (unsigned short*)(ws + 131072);
  unsigned short* fT   = (unsigned short*)(ws + 196608);
  unsigned short* eg   = (unsigned short*)(ws + 67305472ull);
  float*          psums= (float*)(ws + 75694080ull);
  float*          part = (float*)(ws + 75960320ull);

  k_prep<<<dim3(96), dim3(256), 0, stream>>>(conv_w, centroids, Wsw, Cbsw);

  // fused xnorm + projection + logits/exp -> fT, e-images, psums
  k_xproj<<<dim3(32, NB), dim3(512), 0, stream>>>(x, Wsw, Cbsw, conv_b, fT, eg, psums);

  // vlad partials: e(K,L) * f(L,D), split-L into 8 chunks of 512
  k_vlad<<<dim3(512), dim3(256), 0, stream>>>(eg, fT, part);

  k_reduce<<<dim3(NB * KC * DD / 256), dim3(256), 0, stream>>>(part, psums, out);

  (void)in_sizes; (void)n_in; (void)out_size; (void)ws_size;
}